// Round 2
// baseline (422.647 us; speedup 1.0000x reference)
//
#include <hip/hip_runtime.h>
#include <hip/hip_bf16.h>
#include <math.h>

// cummax along axis 1 of [B=16, T=512, H=64, C=128] fp32.
// Flat index: ((b*T + t)*H + h)*C + c -> T-stride = H*C = 8192 floats.
// One thread per float2 column-pair; running max over T.
//
// Parallelism is capped by column count: 65,536 threads = 4 waves/CU =
// 1 wave/SIMD. All latency hiding must come from ILP, so each thread
// explicitly batches BT=16 independent loads into registers before the
// (sequential) max chain, then stores the batch. 16 x 512 B x 4 waves
// = 32 KB in flight per CU >> ~9.2 KB needed for the per-CU HBM share.

#define T_DIM 512
#define HC2 4096          // H*C/2 float2 columns per (b,t) slab
#define BT 16             // time-batch per load burst

__global__ __launch_bounds__(128) void cummax_kernel(const float* __restrict__ in,
                                                     float* __restrict__ out) {
    int gid = blockIdx.x * blockDim.x + threadIdx.x;   // [0, 65536)
    int b   = gid >> 12;          // / HC2
    int cp  = gid & (HC2 - 1);    // float2-column within the batch slab

    const float2* __restrict__ src =
        (const float2*)(in)  + (size_t)b * T_DIM * HC2 + cp;
    float2* __restrict__ dst =
        (float2*)(out) + (size_t)b * T_DIM * HC2 + cp;

    float mx = -INFINITY;
    float my = -INFINITY;

    for (int tb = 0; tb < T_DIM; tb += BT) {
        float2 v[BT];
        // Burst of BT independent loads — all addresses known up front.
        #pragma unroll
        for (int i = 0; i < BT; ++i) {
            v[i] = src[(size_t)(tb + i) * HC2];
        }
        // Sequential max chain (cheap VALU), results written back in-place.
        #pragma unroll
        for (int i = 0; i < BT; ++i) {
            mx = fmaxf(mx, v[i].x);
            my = fmaxf(my, v[i].y);
            v[i].x = mx;
            v[i].y = my;
        }
        // Burst of BT stores.
        #pragma unroll
        for (int i = 0; i < BT; ++i) {
            dst[(size_t)(tb + i) * HC2] = v[i];
        }
    }
}

extern "C" void kernel_launch(void* const* d_in, const int* in_sizes, int n_in,
                              void* d_out, int out_size, void* d_ws, size_t ws_size,
                              hipStream_t stream) {
    const float* in = (const float*)d_in[0];
    float* out = (float*)d_out;

    // 65536 threads: 512 blocks x 128 -> 2 blocks/CU on all 256 CUs.
    cummax_kernel<<<dim3(512), dim3(128), 0, stream>>>(in, out);
}